// Round 3
// baseline (442.356 us; speedup 1.0000x reference)
//
#include <hip/hip_runtime.h>
#include <hip/hip_bf16.h>
#include <stdint.h>

typedef __attribute__((ext_vector_type(8))) short short8;
typedef __attribute__((ext_vector_type(4))) float floatx4;
typedef __attribute__((ext_vector_type(2))) unsigned int uint2v;

#define DEV static __device__ __forceinline__

DEV unsigned short f2bs(float f) {           // f32 -> bf16 bits, RNE
  union { float f; unsigned u; } v; v.f = f;
  unsigned u = v.u;
  u += 0x7fffu + ((u >> 16) & 1u);
  return (unsigned short)(u >> 16);
}
DEV float bs2f(unsigned short s) {
  union { unsigned u; float f; } v; v.u = ((unsigned)s) << 16;
  return v.f;
}
DEV unsigned pack2(float a, float b) {
  return (unsigned)f2bs(a) | ((unsigned)f2bs(b) << 16);
}

DEV void gload_lds16(const void* g, void* l) {
  __builtin_amdgcn_global_load_lds(
      (const __attribute__((address_space(1))) void*)g,
      (__attribute__((address_space(3))) void*)l, 16, 0, 0);
}

static constexpr int Hdim = 1024;
static constexpr int KDim = 512;
static constexpr int NH = 16;
static constexpr int HK = 32;
static constexpr int HV = 64;
static constexpr int Ttok = 8192;
static constexpr int Mtok = 4 * 8192;

// ---------- f32 -> bf16 convert (weights) ----------
__global__ __launch_bounds__(256) void k_cvt(const float4* __restrict__ in,
                                             uint2v* __restrict__ out, int n4) {
  int i = blockIdx.x * 256 + threadIdx.x;
  if (i >= n4) return;
  float4 v = in[i];
  uint2v o;
  o.x = pack2(v.x, v.y);
  o.y = pack2(v.z, v.w);
  out[i] = o;
}

// ---------- rmsnorm(hidden) -> X bf16 ----------
__global__ __launch_bounds__(256) void k_rmsnorm(const float* __restrict__ hs,
                                                 const float* __restrict__ nw,
                                                 uint2v* __restrict__ X) {
  const int token = blockIdx.x;
  const int tid = threadIdx.x;
  float4 h = ((const float4*)(hs + (size_t)token * Hdim))[tid];
  float ss = h.x * h.x + h.y * h.y + h.z * h.z + h.w * h.w;
#pragma unroll
  for (int off = 32; off > 0; off >>= 1) ss += __shfl_down(ss, off, 64);
  __shared__ float red[4];
  const int lane = tid & 63, wid = tid >> 6;
  if (lane == 0) red[wid] = ss;
  __syncthreads();
  float tot = red[0] + red[1] + red[2] + red[3];
  float sc = rsqrtf(tot * (1.0f / Hdim) + 1e-5f);
  float4 w = ((const float4*)nw)[tid];
  uint2v o;
  o.x = pack2(h.x * sc * w.x, h.y * sc * w.y);
  o.y = pack2(h.z * sc * w.z, h.w * sc * w.w);
  X[(size_t)token * 256 + tid] = o;
}

// ---------- 128^2 bf16 GEMM (kept, verified): C = A[M,K] * W[N,K]^T ----------
// EPI 3: store bf16(acc)
template <int EPI>
__global__ __launch_bounds__(256, 2) void k_gemm_bt(
    const unsigned short* __restrict__ A, const unsigned short* __restrict__ Bw,
    void* __restrict__ Cout, const int N, const int K) {
  __shared__ unsigned short As[128 * 64];
  __shared__ unsigned short Bs[128 * 64];
  const int tid = threadIdx.x;
  const int lane = tid & 63;
  const int w = tid >> 6;
  const int wr = w >> 1, wc = w & 1;
  const int m0 = blockIdx.y * 128;
  const int n0 = blockIdx.x * 128;

  floatx4 acc[4][4];
#pragma unroll
  for (int i = 0; i < 4; ++i)
#pragma unroll
    for (int j = 0; j < 4; ++j) acc[i][j] = (floatx4){0.f, 0.f, 0.f, 0.f};

  const int r_a = tid >> 3;
  const int c_a = (tid & 7) * 8;
  const unsigned short* Ag = A + (size_t)(m0 + r_a) * K + c_a;
  const unsigned short* Bg = Bw + (size_t)(n0 + r_a) * K + c_a;
  char* AsDst = (char*)As + tid * 16;
  char* BsDst = (char*)Bs + tid * 16;

  const int frr = lane & 15;
  const int frk = (lane >> 4) * 8;

  for (int k0 = 0; k0 < K; k0 += 64) {
#pragma unroll
    for (int i = 0; i < 4; ++i)
      gload_lds16(Ag + (size_t)i * 32 * K + k0, AsDst + i * 4096);
#pragma unroll
    for (int i = 0; i < 4; ++i)
      gload_lds16(Bg + (size_t)i * 32 * K + k0, BsDst + i * 4096);
    __syncthreads();
#pragma unroll
    for (int kk = 0; kk < 64; kk += 32) {
      short8 a[4], b[4];
#pragma unroll
      for (int mi = 0; mi < 4; ++mi)
        a[mi] = *(const short8*)&As[(wr * 64 + mi * 16 + frr) * 64 + kk + frk];
#pragma unroll
      for (int ni = 0; ni < 4; ++ni)
        b[ni] = *(const short8*)&Bs[(wc * 64 + ni * 16 + frr) * 64 + kk + frk];
#pragma unroll
      for (int mi = 0; mi < 4; ++mi)
#pragma unroll
        for (int ni = 0; ni < 4; ++ni)
          acc[mi][ni] = __builtin_amdgcn_mfma_f32_16x16x32_bf16(
              a[mi], b[ni], acc[mi][ni], 0, 0, 0);
    }
    __syncthreads();
  }

  const int rb = (lane >> 4) * 4;
#pragma unroll
  for (int mi = 0; mi < 4; ++mi)
#pragma unroll
    for (int ni = 0; ni < 4; ++ni) {
      const floatx4 v = acc[mi][ni];
      const int n = n0 + wc * 64 + ni * 16 + (lane & 15);
#pragma unroll
      for (int r = 0; r < 4; ++r) {
        const int m = m0 + wr * 64 + mi * 16 + rb + r;
        const size_t idx = (size_t)m * N + n;
        if (EPI == 0) {
          ((float*)Cout)[idx] = v[r];
        } else {
          ((unsigned short*)Cout)[idx] = f2bs(v[r]);
        }
      }
    }
}

// ---------- 256^2 / BK=64 / 8-wave GEMM, dbuf + counted vmcnt (T3 minimum) ----
// EPI 1: store bf16(sigmoid(acc))   EPI 2: store f32(gate * acc) to d_out
DEV void stage_tile(const unsigned short* __restrict__ G, int ldg,
                    unsigned short* lds, int tid) {
  const unsigned short* src = G + (size_t)(tid >> 3) * ldg + (tid & 7) * 8;
  char* dst = (char*)lds + tid * 16;
#pragma unroll
  for (int i = 0; i < 4; ++i)
    gload_lds16(src + (size_t)(i * 64) * ldg, dst + i * 8192);
}

template <int EPI>
__global__ __launch_bounds__(512, 2) void k_gemm256(
    const unsigned short* __restrict__ A, const unsigned short* __restrict__ Bw,
    void* __restrict__ Cout, const unsigned short* __restrict__ Gate,
    const int N, const int K) {
  __shared__ unsigned short As[2][256 * 64];   // 64 KB
  __shared__ unsigned short Bs[2][256 * 64];   // 64 KB
  const int tid = threadIdx.x;
  const int lane = tid & 63;
  const int w = tid >> 6;             // 0..7
  const int wr = w >> 2, wc = w & 3;  // 2 (M) x 4 (N)

  // bijective XCD swizzle: each XCD gets a contiguous chunk; col-major decode
  // so each XCD's chunk shares one B-panel (L2-resident).
  const int nwg = gridDim.x;
  const int bid = blockIdx.x;
  const int cpx = nwg >> 3;
  const int swz = ((nwg & 7) == 0) ? ((bid & 7) * cpx + (bid >> 3)) : bid;
  const int ncols = N >> 8;
  const int nrows = nwg / ncols;
  const int col = swz / nrows;
  const int row = swz - col * nrows;
  const int m0 = row << 8;
  const int n0 = col << 8;

  floatx4 acc[8][4];
#pragma unroll
  for (int i = 0; i < 8; ++i)
#pragma unroll
    for (int j = 0; j < 4; ++j) acc[i][j] = (floatx4){0.f, 0.f, 0.f, 0.f};

  const unsigned short* Abase = A + (size_t)m0 * K;
  const unsigned short* Bbase = Bw + (size_t)n0 * K;
  const int frr = lane & 15;
  const int frk = (lane >> 4) * 8;
  const int NT = K >> 6;

  // prologue: stage tile 0 into buf 0
  stage_tile(Abase, K, &As[0][0], tid);
  stage_tile(Bbase, K, &Bs[0][0], tid);

  int buf = 0;
  for (int kt = 0; kt < NT; ++kt) {
    if (kt + 1 < NT) {
      stage_tile(Abase + (kt + 1) * 64, K, &As[buf ^ 1][0], tid);
      stage_tile(Bbase + (kt + 1) * 64, K, &Bs[buf ^ 1][0], tid);
      // wait only for the 8 oldest (tile kt); tile kt+1's 8 stay in flight
      asm volatile("s_waitcnt vmcnt(8)" ::: "memory");
    } else {
      asm volatile("s_waitcnt vmcnt(0)" ::: "memory");
    }
    __builtin_amdgcn_sched_barrier(0);
    __builtin_amdgcn_s_barrier();
    __builtin_amdgcn_sched_barrier(0);

    const unsigned short* Asb = &As[buf][0];
    const unsigned short* Bsb = &Bs[buf][0];
#pragma unroll
    for (int kk = 0; kk < 64; kk += 32) {
      short8 bf[4];
#pragma unroll
      for (int ni = 0; ni < 4; ++ni)
        bf[ni] = *(const short8*)&Bsb[(wc * 64 + ni * 16 + frr) * 64 + kk + frk];
#pragma unroll
      for (int mi = 0; mi < 8; ++mi) {
        const short8 af =
            *(const short8*)&Asb[(wr * 128 + mi * 16 + frr) * 64 + kk + frk];
#pragma unroll
        for (int ni = 0; ni < 4; ++ni)
          acc[mi][ni] = __builtin_amdgcn_mfma_f32_16x16x32_bf16(
              af, bf[ni], acc[mi][ni], 0, 0, 0);
      }
    }

    __builtin_amdgcn_sched_barrier(0);
    __builtin_amdgcn_s_barrier();
    __builtin_amdgcn_sched_barrier(0);
    buf ^= 1;
  }

  // epilogue: C/D layout col = lane&15, row = (lane>>4)*4 + r
  const int rb = (lane >> 4) * 4;
#pragma unroll
  for (int mi = 0; mi < 8; ++mi)
#pragma unroll
    for (int ni = 0; ni < 4; ++ni) {
      const floatx4 v = acc[mi][ni];
      const int n = n0 + wc * 64 + ni * 16 + (lane & 15);
#pragma unroll
      for (int r = 0; r < 4; ++r) {
        const int m = m0 + wr * 128 + mi * 16 + rb + r;
        const size_t idx = (size_t)m * N + n;
        if (EPI == 1) {
          float s = 1.0f / (1.0f + __expf(-v[r]));
          ((unsigned short*)Cout)[idx] = f2bs(s);
        } else {
          float g = bs2f(Gate[idx]);
          ((float*)Cout)[idx] = g * v[r];
        }
      }
    }
}

// ---------- q-normalize (folded) + state contraction + head rmsnorm ----------
__global__ __launch_bounds__(256) void k_qstate(const unsigned short* __restrict__ Q,
                                                const float* __restrict__ S,
                                                const float* __restrict__ vnw,
                                                unsigned short* __restrict__ O) {
  __shared__ float Sl[HK * HV];  // 8 KB, one head's state
  __shared__ float Vl[HV];
  const int tid = threadIdx.x;
  const int h = blockIdx.y;
  const int tt0 = blockIdx.x * 256;
  const int b = tt0 / Ttok;
  const float* Sp = S + (size_t)(b * NH + h) * (HK * HV);
#pragma unroll
  for (int i = 0; i < 2; ++i)
    ((float4*)Sl)[tid + i * 256] = ((const float4*)Sp)[tid + i * 256];
  if (tid < HV) Vl[tid] = vnw[tid];
  __syncthreads();

  const int tt = tt0 + tid;
  const unsigned short* qp = Q + (size_t)tt * KDim + h * HK;
  float q[HK];
#pragma unroll
  for (int i = 0; i < 4; ++i) {
    short8 v = ((const short8*)qp)[i];
#pragma unroll
    for (int j = 0; j < 8; ++j) q[8 * i + j] = bs2f((unsigned short)v[j]);
  }
  float ss = 0.f;
#pragma unroll
  for (int k = 0; k < HK; ++k) ss += q[k] * q[k];
  const float inv = 1.0f / fmaxf(sqrtf(ss), 1e-12f);  // fold normalize into o

  float4 o[16];
#pragma unroll
  for (int v = 0; v < 16; ++v) o[v] = (float4){0.f, 0.f, 0.f, 0.f};
#pragma unroll 4
  for (int k = 0; k < HK; ++k) {
    const float qk = q[k];
    const float4* sr = (const float4*)&Sl[k * HV];
#pragma unroll
    for (int v = 0; v < 16; ++v) {
      float4 s = sr[v];
      o[v].x += qk * s.x; o[v].y += qk * s.y;
      o[v].z += qk * s.z; o[v].w += qk * s.w;
    }
  }
  float ss2 = 0.f;
#pragma unroll
  for (int v = 0; v < 16; ++v) {
    o[v].x *= inv; o[v].y *= inv; o[v].z *= inv; o[v].w *= inv;
    ss2 += o[v].x * o[v].x + o[v].y * o[v].y + o[v].z * o[v].z + o[v].w * o[v].w;
  }
  const float sc = rsqrtf(ss2 * (1.0f / HV) + 1e-5f);
  unsigned short* Op = O + (size_t)tt * Hdim + h * HV;
#pragma unroll
  for (int v = 0; v < 16; ++v) {
    float4 wv = ((const float4*)Vl)[v];
    uint2v ov;
    ov.x = pack2(o[v].x * sc * wv.x, o[v].y * sc * wv.y);
    ov.y = pack2(o[v].z * sc * wv.z, o[v].w * sc * wv.w);
    ((uint2v*)Op)[v] = ov;
  }
}

extern "C" void kernel_launch(void* const* d_in, const int* in_sizes, int n_in,
                              void* d_out, int out_size, void* d_ws, size_t ws_size,
                              hipStream_t stream) {
  const float* hs = (const float*)d_in[0];
  const float* Srec = (const float*)d_in[1];
  const float* nw = (const float*)d_in[2];
  const float* qw = (const float*)d_in[3];
  const float* vnw = (const float*)d_in[4];
  const float* ow = (const float*)d_in[5];
  const float* gw = (const float*)d_in[6];

  char* ws = (char*)d_ws;
  unsigned short* X = (unsigned short*)(ws);                          // 64 MB bf16 [M,H]
  unsigned short* Ob = (unsigned short*)(ws + ((size_t)64 << 20));    // 64 MB bf16 [M,VD]
  unsigned short* Gs = (unsigned short*)(ws + ((size_t)128 << 20));   // 64 MB bf16 [M,H]
  unsigned short* Qb = (unsigned short*)(ws + ((size_t)192 << 20));   // 32 MB bf16 [M,KD]
  unsigned short* qwb = (unsigned short*)(ws + ((size_t)256 << 20));  // 1 MB
  unsigned short* gwb = (unsigned short*)(ws + ((size_t)257 << 20));  // 2 MB
  unsigned short* owb = (unsigned short*)(ws + ((size_t)259 << 20));  // 2 MB

  // weights f32 -> bf16
  k_cvt<<<(KDim * Hdim / 4 + 255) / 256, 256, 0, stream>>>(
      (const float4*)qw, (uint2v*)qwb, KDim * Hdim / 4);
  k_cvt<<<(Hdim * Hdim / 4 + 255) / 256, 256, 0, stream>>>(
      (const float4*)gw, (uint2v*)gwb, Hdim * Hdim / 4);
  k_cvt<<<(Hdim * Hdim / 4 + 255) / 256, 256, 0, stream>>>(
      (const float4*)ow, (uint2v*)owb, Hdim * Hdim / 4);

  // x = rmsnorm(hidden) -> bf16
  k_rmsnorm<<<Mtok, 256, 0, stream>>>(hs, nw, (uint2v*)X);

  // Q = X @ q_w^T  (bf16 out)
  k_gemm_bt<3><<<dim3(KDim / 128, Mtok / 128), 256, 0, stream>>>(
      X, qwb, Qb, KDim, Hdim);

  // per-head: normalize-fold + state contraction + rmsnorm -> Ob bf16
  k_qstate<<<dim3(Mtok / 256, NH), 256, 0, stream>>>(Qb, Srec, vnw, Ob);

  // Gs = sigmoid(X @ gate_w^T) -> bf16   (256^2 pipelined GEMM)
  k_gemm256<1><<<(Mtok / 256) * (Hdim / 256), 512, 0, stream>>>(
      X, gwb, Gs, nullptr, Hdim, Hdim);

  // out = Gs * (Ob @ o_w^T) -> f32 d_out (256^2 pipelined GEMM)
  k_gemm256<2><<<(Mtok / 256) * (Hdim / 256), 512, 0, stream>>>(
      Ob, owb, (float*)d_out, Gs, Hdim, Hdim);
}

// Round 4
// 429.135 us; speedup vs baseline: 1.0308x; 1.0308x over previous
//
#include <hip/hip_runtime.h>
#include <hip/hip_bf16.h>
#include <stdint.h>

typedef __attribute__((ext_vector_type(8))) short short8;
typedef __attribute__((ext_vector_type(4))) float floatx4;
typedef __attribute__((ext_vector_type(2))) unsigned int uint2v;

#define DEV static __device__ __forceinline__

DEV unsigned short f2bs(float f) {           // f32 -> bf16 bits, RNE
  union { float f; unsigned u; } v; v.f = f;
  unsigned u = v.u;
  u += 0x7fffu + ((u >> 16) & 1u);
  return (unsigned short)(u >> 16);
}
DEV float bs2f(unsigned short s) {
  union { unsigned u; float f; } v; v.u = ((unsigned)s) << 16;
  return v.f;
}
DEV unsigned pack2(float a, float b) {
  return (unsigned)f2bs(a) | ((unsigned)f2bs(b) << 16);
}

DEV void gload_lds16(const void* g, void* l) {
  __builtin_amdgcn_global_load_lds(
      (const __attribute__((address_space(1))) void*)g,
      (__attribute__((address_space(3))) void*)l, 16, 0, 0);
}

static constexpr int Hdim = 1024;
static constexpr int KDim = 512;
static constexpr int NH = 16;
static constexpr int HK = 32;
static constexpr int HV = 64;
static constexpr int Ttok = 8192;
static constexpr int Mtok = 4 * 8192;

// ---------- f32 -> bf16 convert (weights) ----------
__global__ __launch_bounds__(256) void k_cvt(const float4* __restrict__ in,
                                             uint2v* __restrict__ out, int n4) {
  int i = blockIdx.x * 256 + threadIdx.x;
  if (i >= n4) return;
  float4 v = in[i];
  uint2v o;
  o.x = pack2(v.x, v.y);
  o.y = pack2(v.z, v.w);
  out[i] = o;
}

// ---------- rmsnorm(hidden) -> X bf16 ----------
__global__ __launch_bounds__(256) void k_rmsnorm(const float* __restrict__ hs,
                                                 const float* __restrict__ nw,
                                                 uint2v* __restrict__ X) {
  const int token = blockIdx.x;
  const int tid = threadIdx.x;
  float4 h = ((const float4*)(hs + (size_t)token * Hdim))[tid];
  float ss = h.x * h.x + h.y * h.y + h.z * h.z + h.w * h.w;
#pragma unroll
  for (int off = 32; off > 0; off >>= 1) ss += __shfl_down(ss, off, 64);
  __shared__ float red[4];
  const int lane = tid & 63, wid = tid >> 6;
  if (lane == 0) red[wid] = ss;
  __syncthreads();
  float tot = red[0] + red[1] + red[2] + red[3];
  float sc = rsqrtf(tot * (1.0f / Hdim) + 1e-5f);
  float4 w = ((const float4*)nw)[tid];
  uint2v o;
  o.x = pack2(h.x * sc * w.x, h.y * sc * w.y);
  o.y = pack2(h.z * sc * w.z, h.w * sc * w.w);
  X[(size_t)token * 256 + tid] = o;
}

// ---------- 256^2 / BK=64 / 8-wave GEMM, 4-phase interleave ----------
// T2 swizzle: logical (row r, col c shorts) stored at LDS short idx
//   r*64 + (c ^ ((r&7)*8)).  Write side: linear gload_lds dest + pre-swizzled
//   global source column (rule #21: swizzle source+read, dest stays linear).
DEV void stage_half(const unsigned short* __restrict__ G, int ldg,
                    unsigned short* lds, int tid) {
  const int r = tid >> 3;                              // 0..63 (+64 for rnd 2)
  const int c = ((tid & 7) ^ (r & 7)) * 8;             // pre-swizzled col
  const unsigned short* src = G + (size_t)r * ldg + c;
  char* dst = (char*)lds + tid * 16;
  gload_lds16(src, dst);
  gload_lds16(src + (size_t)64 * ldg, dst + 8192);
}

#define PHASE_SYNC_PRE()                              \
  __builtin_amdgcn_sched_barrier(0);                  \
  __builtin_amdgcn_s_barrier();                       \
  asm volatile("s_waitcnt lgkmcnt(0)" ::: "memory");  \
  __builtin_amdgcn_sched_barrier(0);                  \
  __builtin_amdgcn_s_setprio(1)

#define PHASE_SYNC_POST()                             \
  __builtin_amdgcn_s_setprio(0);                      \
  __builtin_amdgcn_sched_barrier(0);                  \
  __builtin_amdgcn_s_barrier();                       \
  __builtin_amdgcn_sched_barrier(0)

// EPI 1: bf16(sigmoid(acc))   EPI 2: f32(gate*acc)   EPI 3: bf16(acc)
template <int EPI>
__global__ __launch_bounds__(512, 2) void k_gemm256(
    const unsigned short* __restrict__ A, const unsigned short* __restrict__ Bw,
    void* __restrict__ Cout, const unsigned short* __restrict__ Gate,
    const int N, const int K) {
  __shared__ unsigned short As[2][2][128 * 64];   // [slot][half] 64 KB
  __shared__ unsigned short Bs[2][2][128 * 64];   // 64 KB
  const int tid = threadIdx.x;
  const int lane = tid & 63;
  const int w = tid >> 6;             // 0..7
  const int wr = w >> 2, wc = w & 3;  // 2 (M) x 4 (N)
  const int wcH = wc >> 1;            // which B half this wave reads
  const int rB0 = (wc & 1) * 64;      // B row base within half

  // bijective XCD swizzle, col-major decode (XCD chunk shares one B panel)
  const int nwg = gridDim.x;
  const int bid = blockIdx.x;
  const int cpx = nwg >> 3;
  const int swz = ((nwg & 7) == 0) ? ((bid & 7) * cpx + (bid >> 3)) : bid;
  const int ncols = N >> 8;
  const int nrows = nwg / ncols;
  const int col = swz / nrows;
  const int row = swz - col * nrows;
  const int m0 = row << 8, n0 = col << 8;

  floatx4 acc[8][4];
#pragma unroll
  for (int i = 0; i < 8; ++i)
#pragma unroll
    for (int j = 0; j < 4; ++j) acc[i][j] = (floatx4){0.f, 0.f, 0.f, 0.f};

  const unsigned short* Ab = A + (size_t)m0 * K;
  const unsigned short* Bb = Bw + (size_t)n0 * K;
  const int frr = lane & 15;
  const int frk = (lane >> 4) * 8;
  const int asw = (frr & 7) * 8;      // read-side swizzle XOR (shorts)
  const int NT = K >> 6;

  // prologue: tile0 all 4 halves + tile1 A halves; keep tile1's A in flight
  stage_half(Ab, K, &As[0][0][0], tid);
  stage_half(Ab + (size_t)128 * K, K, &As[0][1][0], tid);
  stage_half(Bb, K, &Bs[0][0][0], tid);
  stage_half(Bb + (size_t)128 * K, K, &Bs[0][1][0], tid);
  stage_half(Ab + 64, K, &As[1][0][0], tid);
  stage_half(Ab + (size_t)128 * K + 64, K, &As[1][1][0], tid);
  asm volatile("s_waitcnt vmcnt(4)" ::: "memory");
  __builtin_amdgcn_sched_barrier(0);
  __builtin_amdgcn_s_barrier();

  for (int kt = 0; kt < NT; ++kt) {
    const unsigned short* Ah = &As[kt & 1][wr][0];
    const unsigned short* Bh = &Bs[kt & 1][wcH][0];
    short8 af[2][4], bf[2][2];

    // ---- phase 1: reads A[0..3], B[0..1]; stage Bh0(kt+1); MFMA mi0-3 x ni0-1
#pragma unroll
    for (int kh = 0; kh < 2; ++kh)
#pragma unroll
      for (int mi = 0; mi < 4; ++mi)
        af[kh][mi] = *(const short8*)
            &Ah[(mi * 16 + frr) * 64 + ((kh * 32 + frk) ^ asw)];
#pragma unroll
    for (int kh = 0; kh < 2; ++kh)
#pragma unroll
      for (int ni = 0; ni < 2; ++ni)
        bf[kh][ni] = *(const short8*)
            &Bh[(rB0 + ni * 16 + frr) * 64 + ((kh * 32 + frk) ^ asw)];
    if (kt + 1 < NT)
      stage_half(Bb + (size_t)(kt + 1) * 64, K, &Bs[(kt + 1) & 1][0][0], tid);
    PHASE_SYNC_PRE();
#pragma unroll
    for (int kh = 0; kh < 2; ++kh)
#pragma unroll
      for (int mi = 0; mi < 4; ++mi)
#pragma unroll
        for (int ni = 0; ni < 2; ++ni)
          acc[mi][ni] = __builtin_amdgcn_mfma_f32_16x16x32_bf16(
              af[kh][mi], bf[kh][ni], acc[mi][ni], 0, 0, 0);
    PHASE_SYNC_POST();

    // ---- phase 2: reads B[2..3]; stage Bh1(kt+1); MFMA mi0-3 x ni2-3
#pragma unroll
    for (int kh = 0; kh < 2; ++kh)
#pragma unroll
      for (int ni = 0; ni < 2; ++ni)
        bf[kh][ni] = *(const short8*)
            &Bh[(rB0 + (ni + 2) * 16 + frr) * 64 + ((kh * 32 + frk) ^ asw)];
    if (kt + 1 < NT)
      stage_half(Bb + (size_t)128 * K + (kt + 1) * 64, K,
                 &Bs[(kt + 1) & 1][1][0], tid);
    PHASE_SYNC_PRE();
#pragma unroll
    for (int kh = 0; kh < 2; ++kh)
#pragma unroll
      for (int mi = 0; mi < 4; ++mi)
#pragma unroll
        for (int ni = 0; ni < 2; ++ni)
          acc[mi][ni + 2] = __builtin_amdgcn_mfma_f32_16x16x32_bf16(
              af[kh][mi], bf[kh][ni], acc[mi][ni + 2], 0, 0, 0);
    PHASE_SYNC_POST();

    // ---- phase 3: reads A[4..7]; MFMA mi4-7 x ni2-3 (bf still ni2-3)
#pragma unroll
    for (int kh = 0; kh < 2; ++kh)
#pragma unroll
      for (int mi = 0; mi < 4; ++mi)
        af[kh][mi] = *(const short8*)
            &Ah[((mi + 4) * 16 + frr) * 64 + ((kh * 32 + frk) ^ asw)];
    PHASE_SYNC_PRE();
#pragma unroll
    for (int kh = 0; kh < 2; ++kh)
#pragma unroll
      for (int mi = 0; mi < 4; ++mi)
#pragma unroll
        for (int ni = 0; ni < 2; ++ni)
          acc[mi + 4][ni + 2] = __builtin_amdgcn_mfma_f32_16x16x32_bf16(
              af[kh][mi], bf[kh][ni], acc[mi + 4][ni + 2], 0, 0, 0);
    PHASE_SYNC_POST();

    // ---- phase 4: re-reads B[0..1]; MFMA mi4-7 x ni0-1
#pragma unroll
    for (int kh = 0; kh < 2; ++kh)
#pragma unroll
      for (int ni = 0; ni < 2; ++ni)
        bf[kh][ni] = *(const short8*)
            &Bh[(rB0 + ni * 16 + frr) * 64 + ((kh * 32 + frk) ^ asw)];
    PHASE_SYNC_PRE();
#pragma unroll
    for (int kh = 0; kh < 2; ++kh)
#pragma unroll
      for (int mi = 0; mi < 4; ++mi)
#pragma unroll
        for (int ni = 0; ni < 2; ++ni)
          acc[mi + 4][ni] = __builtin_amdgcn_mfma_f32_16x16x32_bf16(
              af[kh][mi], bf[kh][ni], acc[mi + 4][ni], 0, 0, 0);
    PHASE_SYNC_POST();

    // ---- boundary: stage A halves of kt+2 into slot kt&1 (reads done),
    //      then counted wait: all of tile kt+1 landed, kt+2's A stays in flight
    if (kt + 2 < NT) {
      stage_half(Ab + (size_t)(kt + 2) * 64, K, &As[kt & 1][0][0], tid);
      stage_half(Ab + (size_t)128 * K + (kt + 2) * 64, K, &As[kt & 1][1][0],
                 tid);
      asm volatile("s_waitcnt vmcnt(4)" ::: "memory");
    } else if (kt + 1 < NT) {
      asm volatile("s_waitcnt vmcnt(0)" ::: "memory");
    }
    __builtin_amdgcn_sched_barrier(0);
    __builtin_amdgcn_s_barrier();
    __builtin_amdgcn_sched_barrier(0);
  }

  // epilogue: C/D layout col = lane&15, row = (lane>>4)*4 + r
  const int rb = (lane >> 4) * 4;
#pragma unroll
  for (int mi = 0; mi < 8; ++mi)
#pragma unroll
    for (int ni = 0; ni < 4; ++ni) {
      const floatx4 v = acc[mi][ni];
      const int n = n0 + wc * 64 + ni * 16 + (lane & 15);
#pragma unroll
      for (int r = 0; r < 4; ++r) {
        const int m = m0 + wr * 128 + mi * 16 + rb + r;
        const size_t idx = (size_t)m * N + n;
        if (EPI == 1) {
          float s = 1.0f / (1.0f + __expf(-v[r]));
          ((unsigned short*)Cout)[idx] = f2bs(s);
        } else if (EPI == 2) {
          float g = bs2f(Gate[idx]);
          ((float*)Cout)[idx] = g * v[r];
        } else {
          ((unsigned short*)Cout)[idx] = f2bs(v[r]);
        }
      }
    }
}

// ---------- q-normalize (folded) + state contraction + head rmsnorm ----------
__global__ __launch_bounds__(256) void k_qstate(const unsigned short* __restrict__ Q,
                                                const float* __restrict__ S,
                                                const float* __restrict__ vnw,
                                                unsigned short* __restrict__ O) {
  __shared__ float Sl[HK * HV];  // 8 KB, one head's state
  __shared__ float Vl[HV];
  const int tid = threadIdx.x;
  const int h = blockIdx.y;
  const int tt0 = blockIdx.x * 256;
  const int b = tt0 / Ttok;
  const float* Sp = S + (size_t)(b * NH + h) * (HK * HV);
#pragma unroll
  for (int i = 0; i < 2; ++i)
    ((float4*)Sl)[tid + i * 256] = ((const float4*)Sp)[tid + i * 256];
  if (tid < HV) Vl[tid] = vnw[tid];
  __syncthreads();

  const int tt = tt0 + tid;
  const unsigned short* qp = Q + (size_t)tt * KDim + h * HK;
  float q[HK];
#pragma unroll
  for (int i = 0; i < 4; ++i) {
    short8 v = ((const short8*)qp)[i];
#pragma unroll
    for (int j = 0; j < 8; ++j) q[8 * i + j] = bs2f((unsigned short)v[j]);
  }
  float ss = 0.f;
#pragma unroll
  for (int k = 0; k < HK; ++k) ss += q[k] * q[k];
  const float inv = 1.0f / fmaxf(sqrtf(ss), 1e-12f);  // fold normalize into o

  float4 o[16];
#pragma unroll
  for (int v = 0; v < 16; ++v) o[v] = (float4){0.f, 0.f, 0.f, 0.f};
#pragma unroll 4
  for (int k = 0; k < HK; ++k) {
    const float qk = q[k];
    const float4* sr = (const float4*)&Sl[k * HV];
#pragma unroll
    for (int v = 0; v < 16; ++v) {
      float4 s = sr[v];
      o[v].x += qk * s.x; o[v].y += qk * s.y;
      o[v].z += qk * s.z; o[v].w += qk * s.w;
    }
  }
  float ss2 = 0.f;
#pragma unroll
  for (int v = 0; v < 16; ++v) {
    o[v].x *= inv; o[v].y *= inv; o[v].z *= inv; o[v].w *= inv;
    ss2 += o[v].x * o[v].x + o[v].y * o[v].y + o[v].z * o[v].z + o[v].w * o[v].w;
  }
  const float sc = rsqrtf(ss2 * (1.0f / HV) + 1e-5f);
  unsigned short* Op = O + (size_t)tt * Hdim + h * HV;
#pragma unroll
  for (int v = 0; v < 16; ++v) {
    float4 wv = ((const float4*)Vl)[v];
    uint2v ov;
    ov.x = pack2(o[v].x * sc * wv.x, o[v].y * sc * wv.y);
    ov.y = pack2(o[v].z * sc * wv.z, o[v].w * sc * wv.w);
    ((uint2v*)Op)[v] = ov;
  }
}

extern "C" void kernel_launch(void* const* d_in, const int* in_sizes, int n_in,
                              void* d_out, int out_size, void* d_ws, size_t ws_size,
                              hipStream_t stream) {
  const float* hs = (const float*)d_in[0];
  const float* Srec = (const float*)d_in[1];
  const float* nw = (const float*)d_in[2];
  const float* qw = (const float*)d_in[3];
  const float* vnw = (const float*)d_in[4];
  const float* ow = (const float*)d_in[5];
  const float* gw = (const float*)d_in[6];

  char* ws = (char*)d_ws;
  unsigned short* X = (unsigned short*)(ws);                          // 64 MB bf16 [M,H]
  unsigned short* Ob = (unsigned short*)(ws + ((size_t)64 << 20));    // 64 MB bf16 [M,VD]
  unsigned short* Gs = (unsigned short*)(ws + ((size_t)128 << 20));   // 64 MB bf16 [M,H]
  unsigned short* Qb = (unsigned short*)(ws + ((size_t)192 << 20));   // 32 MB bf16 [M,KD]
  unsigned short* qwb = (unsigned short*)(ws + ((size_t)256 << 20));  // 1 MB
  unsigned short* gwb = (unsigned short*)(ws + ((size_t)257 << 20));  // 2 MB
  unsigned short* owb = (unsigned short*)(ws + ((size_t)259 << 20));  // 2 MB

  // weights f32 -> bf16
  k_cvt<<<(KDim * Hdim / 4 + 255) / 256, 256, 0, stream>>>(
      (const float4*)qw, (uint2v*)qwb, KDim * Hdim / 4);
  k_cvt<<<(Hdim * Hdim / 4 + 255) / 256, 256, 0, stream>>>(
      (const float4*)gw, (uint2v*)gwb, Hdim * Hdim / 4);
  k_cvt<<<(Hdim * Hdim / 4 + 255) / 256, 256, 0, stream>>>(
      (const float4*)ow, (uint2v*)owb, Hdim * Hdim / 4);

  // x = rmsnorm(hidden) -> bf16
  k_rmsnorm<<<Mtok, 256, 0, stream>>>(hs, nw, (uint2v*)X);

  // Q = X @ q_w^T  (bf16 out)
  k_gemm256<3><<<(Mtok / 256) * (KDim / 256), 512, 0, stream>>>(
      X, qwb, Qb, nullptr, KDim, Hdim);

  // per-head: normalize-fold + state contraction + rmsnorm -> Ob bf16
  k_qstate<<<dim3(Mtok / 256, NH), 256, 0, stream>>>(Qb, Srec, vnw, Ob);

  // Gs = sigmoid(X @ gate_w^T) -> bf16
  k_gemm256<1><<<(Mtok / 256) * (Hdim / 256), 512, 0, stream>>>(
      X, gwb, Gs, nullptr, Hdim, Hdim);

  // out = Gs * (Ob @ o_w^T) -> f32 d_out
  k_gemm256<2><<<(Mtok / 256) * (Hdim / 256), 512, 0, stream>>>(
      Ob, owb, (float*)d_out, Gs, Hdim, Hdim);
}

// Round 5
// 410.952 us; speedup vs baseline: 1.0764x; 1.0442x over previous
//
#include <hip/hip_runtime.h>
#include <hip/hip_bf16.h>
#include <stdint.h>

typedef __attribute__((ext_vector_type(8))) short short8;
typedef __attribute__((ext_vector_type(4))) float floatx4;
typedef __attribute__((ext_vector_type(2))) unsigned int uint2v;

#define DEV static __device__ __forceinline__
#define FENCE() asm volatile("" ::: "memory")

DEV unsigned short f2bs(float f) {           // f32 -> bf16 bits, RNE
  union { float f; unsigned u; } v; v.f = f;
  unsigned u = v.u;
  u += 0x7fffu + ((u >> 16) & 1u);
  return (unsigned short)(u >> 16);
}
DEV float bs2f(unsigned short s) {
  union { unsigned u; float f; } v; v.u = ((unsigned)s) << 16;
  return v.f;
}
DEV unsigned pack2(float a, float b) {
  return (unsigned)f2bs(a) | ((unsigned)f2bs(b) << 16);
}

DEV void gload_lds16(const void* g, void* l) {
  __builtin_amdgcn_global_load_lds(
      (const __attribute__((address_space(1))) void*)g,
      (__attribute__((address_space(3))) void*)l, 16, 0, 0);
}

static constexpr int Hdim = 1024;
static constexpr int KDim = 512;
static constexpr int NH = 16;
static constexpr int HK = 32;
static constexpr int HV = 64;
static constexpr int Ttok = 8192;
static constexpr int Mtok = 4 * 8192;

// ---------- f32 -> bf16 convert (weights) ----------
__global__ __launch_bounds__(256) void k_cvt(const float4* __restrict__ in,
                                             uint2v* __restrict__ out, int n4) {
  int i = blockIdx.x * 256 + threadIdx.x;
  if (i >= n4) return;
  float4 v = in[i];
  uint2v o;
  o.x = pack2(v.x, v.y);
  o.y = pack2(v.z, v.w);
  out[i] = o;
}

// ---------- rmsnorm(hidden) -> X bf16 ----------
__global__ __launch_bounds__(256) void k_rmsnorm(const float* __restrict__ hs,
                                                 const float* __restrict__ nw,
                                                 uint2v* __restrict__ X) {
  const int token = blockIdx.x;
  const int tid = threadIdx.x;
  float4 h = ((const float4*)(hs + (size_t)token * Hdim))[tid];
  float ss = h.x * h.x + h.y * h.y + h.z * h.z + h.w * h.w;
#pragma unroll
  for (int off = 32; off > 0; off >>= 1) ss += __shfl_down(ss, off, 64);
  __shared__ float red[4];
  const int lane = tid & 63, wid = tid >> 6;
  if (lane == 0) red[wid] = ss;
  __syncthreads();
  float tot = red[0] + red[1] + red[2] + red[3];
  float sc = rsqrtf(tot * (1.0f / Hdim) + 1e-5f);
  float4 w = ((const float4*)nw)[tid];
  uint2v o;
  o.x = pack2(h.x * sc * w.x, h.y * sc * w.y);
  o.y = pack2(h.z * sc * w.z, h.w * sc * w.w);
  X[(size_t)token * 256 + tid] = o;
}

// ---------- 256^2 / BK=64 / 8-wave GEMM, 4-phase, compiler-free sched ------
// T2 swizzle: logical (row r, col c shorts) stored at LDS short idx
//   r*64 + (c ^ ((r&7)*8)).  Write side: linear gload_lds dest + pre-swizzled
//   global source column (rule #21).
DEV void stage_half(const unsigned short* __restrict__ G, int ldg,
                    unsigned short* lds, int tid) {
  const int r = tid >> 3;                              // 0..63
  const int c = ((tid & 7) ^ (r & 7)) * 8;             // pre-swizzled col
  const unsigned short* src = G + (size_t)r * ldg + c;
  char* dst = (char*)lds + tid * 16;
  gload_lds16(src, dst);
  gload_lds16(src + (size_t)64 * ldg, dst + 8192);
}

// EPI 1: bf16(sigmoid(acc))   EPI 2: f32(gate*acc)   EPI 3: bf16(acc)
template <int EPI>
__global__ __launch_bounds__(512, 2) void k_gemm256(
    const unsigned short* __restrict__ A, const unsigned short* __restrict__ Bw,
    void* __restrict__ Cout, const unsigned short* __restrict__ Gate,
    const int N, const int K) {
  __shared__ unsigned short As[2][2][128 * 64];   // [slot][half] 64 KB
  __shared__ unsigned short Bs[2][2][128 * 64];   // 64 KB
  const int tid = threadIdx.x;
  const int lane = tid & 63;
  const int w = tid >> 6;             // 0..7
  const int wr = w >> 2, wc = w & 3;  // 2 (M) x 4 (N)
  const int wcH = wc >> 1;            // which B half this wave reads
  const int rB0 = (wc & 1) * 64;      // B row base within half

  // bijective XCD swizzle, col-major decode (XCD chunk shares one B panel)
  const int nwg = gridDim.x;
  const int bid = blockIdx.x;
  const int cpx = nwg >> 3;
  const int swz = ((nwg & 7) == 0) ? ((bid & 7) * cpx + (bid >> 3)) : bid;
  const int ncols = N >> 8;
  const int nrows = nwg / ncols;
  const int col = swz / nrows;
  const int row = swz - col * nrows;
  const int m0 = row << 8, n0 = col << 8;

  floatx4 acc[8][4];
#pragma unroll
  for (int i = 0; i < 8; ++i)
#pragma unroll
    for (int j = 0; j < 4; ++j) acc[i][j] = (floatx4){0.f, 0.f, 0.f, 0.f};

  const unsigned short* Ab = A + (size_t)m0 * K;
  const unsigned short* Bb = Bw + (size_t)n0 * K;
  const int frr = lane & 15;
  const int frk = (lane >> 4) * 8;
  const int asw = (frr & 7) * 8;      // read-side swizzle XOR (shorts)
  const int NT = K >> 6;

  // prologue: tile0 all 4 halves + tile1 A halves; keep tile1's A in flight
  stage_half(Ab, K, &As[0][0][0], tid);
  stage_half(Ab + (size_t)128 * K, K, &As[0][1][0], tid);
  stage_half(Bb, K, &Bs[0][0][0], tid);
  stage_half(Bb + (size_t)128 * K, K, &Bs[0][1][0], tid);
  stage_half(Ab + 64, K, &As[1][0][0], tid);
  stage_half(Ab + (size_t)128 * K + 64, K, &As[1][1][0], tid);
  asm volatile("s_waitcnt vmcnt(4)" ::: "memory");
  __builtin_amdgcn_s_barrier();
  FENCE();

  for (int kt = 0; kt < NT; ++kt) {
    const unsigned short* Ah = &As[kt & 1][wr][0];
    const unsigned short* Bh = &Bs[kt & 1][wcH][0];
    short8 af[2][4], af2[2][4], bf[2][4];

    // ---- phase 1: load all B frags (8) + low A frags (8); stage Bh0(kt+1)
#pragma unroll
    for (int kh = 0; kh < 2; ++kh)
#pragma unroll
      for (int ni = 0; ni < 4; ++ni)
        bf[kh][ni] = *(const short8*)
            &Bh[(rB0 + ni * 16 + frr) * 64 + ((kh * 32 + frk) ^ asw)];
#pragma unroll
    for (int kh = 0; kh < 2; ++kh)
#pragma unroll
      for (int mi = 0; mi < 4; ++mi)
        af[kh][mi] = *(const short8*)
            &Ah[(mi * 16 + frr) * 64 + ((kh * 32 + frk) ^ asw)];
    if (kt + 1 < NT)
      stage_half(Bb + (size_t)(kt + 1) * 64, K, &Bs[(kt + 1) & 1][0][0], tid);
    __builtin_amdgcn_s_barrier();
    __builtin_amdgcn_s_setprio(1);
#pragma unroll
    for (int kh = 0; kh < 2; ++kh)
#pragma unroll
      for (int mi = 0; mi < 4; ++mi)
#pragma unroll
        for (int ni = 0; ni < 2; ++ni)
          acc[mi][ni] = __builtin_amdgcn_mfma_f32_16x16x32_bf16(
              af[kh][mi], bf[kh][ni], acc[mi][ni], 0, 0, 0);
    __builtin_amdgcn_s_setprio(0);
    __builtin_amdgcn_s_barrier();

    // ---- phase 2: no loads; stage Bh1(kt+1); MFMA mi0-3 x ni2-3
    if (kt + 1 < NT)
      stage_half(Bb + (size_t)128 * K + (kt + 1) * 64, K,
                 &Bs[(kt + 1) & 1][1][0], tid);
    __builtin_amdgcn_s_barrier();
    __builtin_amdgcn_s_setprio(1);
#pragma unroll
    for (int kh = 0; kh < 2; ++kh)
#pragma unroll
      for (int mi = 0; mi < 4; ++mi)
#pragma unroll
        for (int ni = 0; ni < 2; ++ni)
          acc[mi][ni + 2] = __builtin_amdgcn_mfma_f32_16x16x32_bf16(
              af[kh][mi], bf[kh][ni + 2], acc[mi][ni + 2], 0, 0, 0);
    __builtin_amdgcn_s_setprio(0);
    __builtin_amdgcn_s_barrier();

    // ---- phase 3: load high A frags (8); MFMA mi4-7 x ni2-3
#pragma unroll
    for (int kh = 0; kh < 2; ++kh)
#pragma unroll
      for (int mi = 0; mi < 4; ++mi)
        af2[kh][mi] = *(const short8*)
            &Ah[((mi + 4) * 16 + frr) * 64 + ((kh * 32 + frk) ^ asw)];
    __builtin_amdgcn_s_barrier();
    __builtin_amdgcn_s_setprio(1);
#pragma unroll
    for (int kh = 0; kh < 2; ++kh)
#pragma unroll
      for (int mi = 0; mi < 4; ++mi)
#pragma unroll
        for (int ni = 0; ni < 2; ++ni)
          acc[mi + 4][ni + 2] = __builtin_amdgcn_mfma_f32_16x16x32_bf16(
              af2[kh][mi], bf[kh][ni + 2], acc[mi + 4][ni + 2], 0, 0, 0);
    __builtin_amdgcn_s_setprio(0);
    __builtin_amdgcn_s_barrier();

    // ---- phase 4: no loads; MFMA mi4-7 x ni0-1
    __builtin_amdgcn_s_barrier();
    __builtin_amdgcn_s_setprio(1);
#pragma unroll
    for (int kh = 0; kh < 2; ++kh)
#pragma unroll
      for (int mi = 0; mi < 4; ++mi)
#pragma unroll
        for (int ni = 0; ni < 2; ++ni)
          acc[mi + 4][ni] = __builtin_amdgcn_mfma_f32_16x16x32_bf16(
              af2[kh][mi], bf[kh][ni], acc[mi + 4][ni], 0, 0, 0);
    __builtin_amdgcn_s_setprio(0);

    // ---- boundary: stage A halves of kt+2 into slot kt&1 (reads done),
    //      counted wait: tile kt+1 fully landed, kt+2's A stays in flight
    FENCE();
    if (kt + 2 < NT) {
      stage_half(Ab + (size_t)(kt + 2) * 64, K, &As[kt & 1][0][0], tid);
      stage_half(Ab + (size_t)128 * K + (kt + 2) * 64, K, &As[kt & 1][1][0],
                 tid);
      asm volatile("s_waitcnt vmcnt(4)" ::: "memory");
    } else if (kt + 1 < NT) {
      asm volatile("s_waitcnt vmcnt(0)" ::: "memory");
    }
    __builtin_amdgcn_s_barrier();
    FENCE();
  }

  // epilogue: C/D layout col = lane&15, row = (lane>>4)*4 + r
  const int rb = (lane >> 4) * 4;
#pragma unroll
  for (int mi = 0; mi < 8; ++mi)
#pragma unroll
    for (int ni = 0; ni < 4; ++ni) {
      const floatx4 v = acc[mi][ni];
      const int n = n0 + wc * 64 + ni * 16 + (lane & 15);
#pragma unroll
      for (int r = 0; r < 4; ++r) {
        const int m = m0 + wr * 128 + mi * 16 + rb + r;
        const size_t idx = (size_t)m * N + n;
        if (EPI == 1) {
          float s = 1.0f / (1.0f + __expf(-v[r]));
          ((unsigned short*)Cout)[idx] = f2bs(s);
        } else if (EPI == 2) {
          float g = bs2f(Gate[idx]);
          ((float*)Cout)[idx] = g * v[r];
        } else {
          ((unsigned short*)Cout)[idx] = f2bs(v[r]);
        }
      }
    }
}

// ---------- q-normalize (folded) + state contraction + head rmsnorm ----------
__global__ __launch_bounds__(256) void k_qstate(const unsigned short* __restrict__ Q,
                                                const float* __restrict__ S,
                                                const float* __restrict__ vnw,
                                                unsigned short* __restrict__ O) {
  __shared__ float Sl[HK * HV];  // 8 KB, one head's state
  __shared__ float Vl[HV];
  const int tid = threadIdx.x;
  const int h = blockIdx.y;
  const int tt0 = blockIdx.x * 256;
  const int b = tt0 / Ttok;
  const float* Sp = S + (size_t)(b * NH + h) * (HK * HV);
#pragma unroll
  for (int i = 0; i < 2; ++i)
    ((float4*)Sl)[tid + i * 256] = ((const float4*)Sp)[tid + i * 256];
  if (tid < HV) Vl[tid] = vnw[tid];
  __syncthreads();

  const int tt = tt0 + tid;
  const unsigned short* qp = Q + (size_t)tt * KDim + h * HK;
  float q[HK];
#pragma unroll
  for (int i = 0; i < 4; ++i) {
    short8 v = ((const short8*)qp)[i];
#pragma unroll
    for (int j = 0; j < 8; ++j) q[8 * i + j] = bs2f((unsigned short)v[j]);
  }
  float ss = 0.f;
#pragma unroll
  for (int k = 0; k < HK; ++k) ss += q[k] * q[k];
  const float inv = 1.0f / fmaxf(sqrtf(ss), 1e-12f);  // fold normalize into o

  float4 o[16];
#pragma unroll
  for (int v = 0; v < 16; ++v) o[v] = (float4){0.f, 0.f, 0.f, 0.f};
#pragma unroll 4
  for (int k = 0; k < HK; ++k) {
    const float qk = q[k];
    const float4* sr = (const float4*)&Sl[k * HV];
#pragma unroll
    for (int v = 0; v < 16; ++v) {
      float4 s = sr[v];
      o[v].x += qk * s.x; o[v].y += qk * s.y;
      o[v].z += qk * s.z; o[v].w += qk * s.w;
    }
  }
  float ss2 = 0.f;
#pragma unroll
  for (int v = 0; v < 16; ++v) {
    o[v].x *= inv; o[v].y *= inv; o[v].z *= inv; o[v].w *= inv;
    ss2 += o[v].x * o[v].x + o[v].y * o[v].y + o[v].z * o[v].z + o[v].w * o[v].w;
  }
  const float sc = rsqrtf(ss2 * (1.0f / HV) + 1e-5f);
  unsigned short* Op = O + (size_t)tt * Hdim + h * HV;
#pragma unroll
  for (int v = 0; v < 16; ++v) {
    float4 wv = ((const float4*)Vl)[v];
    uint2v ov;
    ov.x = pack2(o[v].x * sc * wv.x, o[v].y * sc * wv.y);
    ov.y = pack2(o[v].z * sc * wv.z, o[v].w * sc * wv.w);
    ((uint2v*)Op)[v] = ov;
  }
}

extern "C" void kernel_launch(void* const* d_in, const int* in_sizes, int n_in,
                              void* d_out, int out_size, void* d_ws, size_t ws_size,
                              hipStream_t stream) {
  const float* hs = (const float*)d_in[0];
  const float* Srec = (const float*)d_in[1];
  const float* nw = (const float*)d_in[2];
  const float* qw = (const float*)d_in[3];
  const float* vnw = (const float*)d_in[4];
  const float* ow = (const float*)d_in[5];
  const float* gw = (const float*)d_in[6];

  char* ws = (char*)d_ws;
  unsigned short* X = (unsigned short*)(ws);                          // 64 MB bf16 [M,H]
  unsigned short* Ob = (unsigned short*)(ws + ((size_t)64 << 20));    // 64 MB bf16 [M,VD]
  unsigned short* Gs = (unsigned short*)(ws + ((size_t)128 << 20));   // 64 MB bf16 [M,H]
  unsigned short* Qb = (unsigned short*)(ws + ((size_t)192 << 20));   // 32 MB bf16 [M,KD]
  unsigned short* qwb = (unsigned short*)(ws + ((size_t)256 << 20));  // 1 MB
  unsigned short* gwb = (unsigned short*)(ws + ((size_t)257 << 20));  // 2 MB
  unsigned short* owb = (unsigned short*)(ws + ((size_t)259 << 20));  // 2 MB

  // weights f32 -> bf16
  k_cvt<<<(KDim * Hdim / 4 + 255) / 256, 256, 0, stream>>>(
      (const float4*)qw, (uint2v*)qwb, KDim * Hdim / 4);
  k_cvt<<<(Hdim * Hdim / 4 + 255) / 256, 256, 0, stream>>>(
      (const float4*)gw, (uint2v*)gwb, Hdim * Hdim / 4);
  k_cvt<<<(Hdim * Hdim / 4 + 255) / 256, 256, 0, stream>>>(
      (const float4*)ow, (uint2v*)owb, Hdim * Hdim / 4);

  // x = rmsnorm(hidden) -> bf16
  k_rmsnorm<<<Mtok, 256, 0, stream>>>(hs, nw, (uint2v*)X);

  // Q = X @ q_w^T  (bf16 out)
  k_gemm256<3><<<(Mtok / 256) * (KDim / 256), 512, 0, stream>>>(
      X, qwb, Qb, nullptr, KDim, Hdim);

  // per-head: normalize-fold + state contraction + rmsnorm -> Ob bf16
  k_qstate<<<dim3(Mtok / 256, NH), 256, 0, stream>>>(Qb, Srec, vnw, Ob);

  // Gs = sigmoid(X @ gate_w^T) -> bf16
  k_gemm256<1><<<(Mtok / 256) * (Hdim / 256), 512, 0, stream>>>(
      X, gwb, Gs, nullptr, Hdim, Hdim);

  // out = Gs * (Ob @ o_w^T) -> f32 d_out
  k_gemm256<2><<<(Mtok / 256) * (Hdim / 256), 512, 0, stream>>>(
      Ob, owb, (float*)d_out, Gs, Hdim, Hdim);
}

// Round 6
// 318.481 us; speedup vs baseline: 1.3890x; 1.2904x over previous
//
#include <hip/hip_runtime.h>
#include <hip/hip_bf16.h>
#include <stdint.h>

typedef __attribute__((ext_vector_type(8))) short short8;
typedef __attribute__((ext_vector_type(4))) float floatx4;
typedef __attribute__((ext_vector_type(2))) unsigned int uint2v;

#define DEV static __device__ __forceinline__

DEV unsigned short f2bs(float f) {           // f32 -> bf16 bits, RNE
  union { float f; unsigned u; } v; v.f = f;
  unsigned u = v.u;
  u += 0x7fffu + ((u >> 16) & 1u);
  return (unsigned short)(u >> 16);
}
DEV float bs2f(unsigned short s) {
  union { unsigned u; float f; } v; v.u = ((unsigned)s) << 16;
  return v.f;
}
DEV unsigned pack2(float a, float b) {
  return (unsigned)f2bs(a) | ((unsigned)f2bs(b) << 16);
}

DEV void gload_lds16(const void* g, void* l) {
  __builtin_amdgcn_global_load_lds(
      (const __attribute__((address_space(1))) void*)g,
      (__attribute__((address_space(3))) void*)l, 16, 0, 0);
}

static constexpr int Hdim = 1024;
static constexpr int KDim = 512;
static constexpr int NH = 16;
static constexpr int HK = 32;
static constexpr int HV = 64;
static constexpr int Mtok = 4 * 8192;

// ---------- f32 -> bf16 convert (weights) ----------
__global__ __launch_bounds__(256) void k_cvt(const float4* __restrict__ in,
                                             uint2v* __restrict__ out, int n4) {
  int i = blockIdx.x * 256 + threadIdx.x;
  if (i >= n4) return;
  float4 v = in[i];
  uint2v o;
  o.x = pack2(v.x, v.y);
  o.y = pack2(v.z, v.w);
  out[i] = o;
}

// ---------- S -> S^T bf16:  St[b][h][v][k] = S[b][h][k][v] ----------
__global__ __launch_bounds__(256) void k_cvts(const float* __restrict__ S,
                                              unsigned short* __restrict__ St) {
  int i = blockIdx.x * 256 + threadIdx.x;      // over out idx, 4*16*64*32
  if (i >= 4 * NH * HV * HK) return;
  int k = i & 31, v = (i >> 5) & 63, bh = i >> 11;
  St[i] = f2bs(S[(size_t)(bh * HK + k) * HV + v]);
}

// ---------- rmsnorm(hidden) -> X bf16 ----------
__global__ __launch_bounds__(256) void k_rmsnorm(const float* __restrict__ hs,
                                                 const float* __restrict__ nw,
                                                 uint2v* __restrict__ X) {
  const int token = blockIdx.x;
  const int tid = threadIdx.x;
  float4 h = ((const float4*)(hs + (size_t)token * Hdim))[tid];
  float ss = h.x * h.x + h.y * h.y + h.z * h.z + h.w * h.w;
#pragma unroll
  for (int off = 32; off > 0; off >>= 1) ss += __shfl_down(ss, off, 64);
  __shared__ float red[4];
  const int lane = tid & 63, wid = tid >> 6;
  if (lane == 0) red[wid] = ss;
  __syncthreads();
  float tot = red[0] + red[1] + red[2] + red[3];
  float sc = rsqrtf(tot * (1.0f / Hdim) + 1e-5f);
  float4 w = ((const float4*)nw)[tid];
  uint2v o;
  o.x = pack2(h.x * sc * w.x, h.y * sc * w.y);
  o.y = pack2(h.z * sc * w.z, h.w * sc * w.w);
  X[(size_t)token * 256 + tid] = o;
}

// ---------- shared 128^2 / BK=64 GEMM core: acc += A[M,K] * W[N,K]^T --------
// As/Bs: 128*64 shorts each. Ends with __syncthreads (LDS reusable after).
DEV void gemm128(const unsigned short* __restrict__ A,
                 const unsigned short* __restrict__ Bw, const int K,
                 const int m0, const int n0, unsigned short* As,
                 unsigned short* Bs, floatx4 (&acc)[4][4], const int tid) {
  const int lane = tid & 63;
  const int w = tid >> 6;
  const int wr = w >> 1, wc = w & 1;
  const int r_a = tid >> 3;
  const int c_a = (tid & 7) * 8;
  const unsigned short* Ag = A + (size_t)(m0 + r_a) * K + c_a;
  const unsigned short* Bg = Bw + (size_t)(n0 + r_a) * K + c_a;
  char* AsDst = (char*)As + tid * 16;
  char* BsDst = (char*)Bs + tid * 16;
  const int frr = lane & 15;
  const int frk = (lane >> 4) * 8;

  for (int k0 = 0; k0 < K; k0 += 64) {
#pragma unroll
    for (int i = 0; i < 4; ++i)
      gload_lds16(Ag + (size_t)i * 32 * K + k0, AsDst + i * 4096);
#pragma unroll
    for (int i = 0; i < 4; ++i)
      gload_lds16(Bg + (size_t)i * 32 * K + k0, BsDst + i * 4096);
    __syncthreads();
#pragma unroll
    for (int kk = 0; kk < 64; kk += 32) {
      short8 a[4], b[4];
#pragma unroll
      for (int mi = 0; mi < 4; ++mi)
        a[mi] = *(const short8*)&As[(wr * 64 + mi * 16 + frr) * 64 + kk + frk];
#pragma unroll
      for (int ni = 0; ni < 4; ++ni)
        b[ni] = *(const short8*)&Bs[(wc * 64 + ni * 16 + frr) * 64 + kk + frk];
#pragma unroll
      for (int mi = 0; mi < 4; ++mi)
#pragma unroll
        for (int ni = 0; ni < 4; ++ni)
          acc[mi][ni] = __builtin_amdgcn_mfma_f32_16x16x32_bf16(
              a[mi], b[ni], acc[mi][ni], 0, 0, 0);
    }
    __syncthreads();
  }
}

// ---------- fused gate+o:  out = sigmoid(X@gw^T) * (Ob@ow^T), f32 ----------
__global__ __launch_bounds__(256, 2) void k_fused_go(
    const unsigned short* __restrict__ X, const unsigned short* __restrict__ Ob,
    const unsigned short* __restrict__ gwb,
    const unsigned short* __restrict__ owb, float* __restrict__ out) {
  __shared__ unsigned short LD[128 * 128];
  unsigned short* As = LD;
  unsigned short* Bs = LD + 128 * 64;
  const int tid = threadIdx.x;
  const int lane = tid & 63;
  const int w = tid >> 6;
  const int wr = w >> 1, wc = w & 1;
  const int m0 = blockIdx.y * 128;
  const int n0 = blockIdx.x * 128;

  floatx4 acc[4][4];
#pragma unroll
  for (int i = 0; i < 4; ++i)
#pragma unroll
    for (int j = 0; j < 4; ++j) acc[i][j] = (floatx4){0.f, 0.f, 0.f, 0.f};

  // pass 1: gate
  gemm128(X, gwb, Hdim, m0, n0, As, Bs, acc, tid);

  // sigmoid -> packed bf16 stash (same precision as old Gs bf16 buffer)
  unsigned pg[4][4][2];
#pragma unroll
  for (int mi = 0; mi < 4; ++mi)
#pragma unroll
    for (int ni = 0; ni < 4; ++ni) {
      float s0 = 1.0f / (1.0f + __expf(-acc[mi][ni][0]));
      float s1 = 1.0f / (1.0f + __expf(-acc[mi][ni][1]));
      float s2 = 1.0f / (1.0f + __expf(-acc[mi][ni][2]));
      float s3 = 1.0f / (1.0f + __expf(-acc[mi][ni][3]));
      pg[mi][ni][0] = pack2(s0, s1);
      pg[mi][ni][1] = pack2(s2, s3);
      acc[mi][ni] = (floatx4){0.f, 0.f, 0.f, 0.f};
    }

  // pass 2: o-proj
  gemm128(Ob, owb, Hdim, m0, n0, As, Bs, acc, tid);

  // epilogue: C/D layout col = lane&15, row = (lane>>4)*4 + r
  const int rb = (lane >> 4) * 4;
#pragma unroll
  for (int mi = 0; mi < 4; ++mi)
#pragma unroll
    for (int ni = 0; ni < 4; ++ni) {
      const int n = n0 + wc * 64 + ni * 16 + (lane & 15);
#pragma unroll
      for (int r = 0; r < 4; ++r) {
        const int m = m0 + wr * 64 + mi * 16 + rb + r;
        float g = bs2f((unsigned short)(pg[mi][ni][r >> 1] >> ((r & 1) * 16)));
        out[(size_t)m * Hdim + n] = g * acc[mi][ni][r];
      }
    }
}

// ---------- fused q-path: q=X@qw^T -> L2-normalize per head -> @S -> rmsnorm
// tile: 128 tokens x 128 q-dims = 4 full heads. Writes Ob bf16 directly.
__global__ __launch_bounds__(256, 2) void k_fused_q(
    const unsigned short* __restrict__ X, const unsigned short* __restrict__ qwb,
    const unsigned short* __restrict__ St, const float* __restrict__ vnw,
    unsigned short* __restrict__ Ob) {
  __shared__ unsigned short LD[128 * 128];   // As|Bs during GEMM, then q-tile
  unsigned short* As = LD;
  unsigned short* Bs = LD + 128 * 64;
  const int tid = threadIdx.x;
  const int lane = tid & 63;
  const int w = tid >> 6;
  const int wr = w >> 1, wc = w & 1;
  const int m0 = blockIdx.y * 128;
  const int n0 = blockIdx.x * 128;   // q-dim base; heads h0..h0+3
  const int h0 = n0 >> 5;
  const int batch = m0 >> 13;        // 8192 tokens per batch

  floatx4 acc[4][4];
#pragma unroll
  for (int i = 0; i < 4; ++i)
#pragma unroll
    for (int j = 0; j < 4; ++j) acc[i][j] = (floatx4){0.f, 0.f, 0.f, 0.f};

  gemm128(X, qwb, Hdim, m0, n0, As, Bs, acc, tid);

  // per-(row,head) L2 norm over 32 dims = 2 ni-frags x 16 lanes, then scale,
  // then store normalized q bf16 into swizzled LDS tile qt[m][c^((m&7)*8)].
  const int rb = (lane >> 4) * 4;
  const int frr = lane & 15;
#pragma unroll
  for (int mi = 0; mi < 4; ++mi)
#pragma unroll
    for (int p = 0; p < 2; ++p) {      // head-half: ni = 2p, 2p+1
#pragma unroll
      for (int r = 0; r < 4; ++r) {
        float v0 = acc[mi][2 * p][r], v1 = acc[mi][2 * p + 1][r];
        float ss = v0 * v0 + v1 * v1;
        ss += __shfl_xor(ss, 1, 64);
        ss += __shfl_xor(ss, 2, 64);
        ss += __shfl_xor(ss, 4, 64);
        ss += __shfl_xor(ss, 8, 64);
        const float inv = 1.0f / fmaxf(sqrtf(ss), 1e-12f);
        const int m = wr * 64 + mi * 16 + rb + r;
        const int c0 = wc * 64 + p * 32 + frr;
        const int sw = (m & 7) * 8;
        LD[m * 128 + (c0 ^ sw)] = f2bs(v0 * inv);
        LD[m * 128 + ((c0 + 16) ^ sw)] = f2bs(v1 * inv);
      }
    }
  __syncthreads();

  // contraction: per head hh, o[32w..32w+31][64] = qn[.,32] @ St[h]^T via MFMA
  // wave w owns token rows m = w*32 .. w*32+31.
  const int frk = (lane >> 4) * 8;   // k sub-range within K=32
  float wv[4];
#pragma unroll
  for (int ni = 0; ni < 4; ++ni) wv[ni] = vnw[ni * 16 + frr];

#pragma unroll
  for (int hh = 0; hh < 4; ++hh) {
    const unsigned short* Sp =
        St + (size_t)(batch * NH + h0 + hh) * (HV * HK);
    short8 bfr[4];
#pragma unroll
    for (int ni = 0; ni < 4; ++ni)
      bfr[ni] = *(const short8*)&Sp[(ni * 16 + frr) * HK + frk];
    floatx4 acc2[2][4];
#pragma unroll
    for (int i = 0; i < 2; ++i)
#pragma unroll
      for (int j = 0; j < 4; ++j) acc2[i][j] = (floatx4){0.f, 0.f, 0.f, 0.f};
    short8 af[2];
#pragma unroll
    for (int mi2 = 0; mi2 < 2; ++mi2) {
      const int m = w * 32 + mi2 * 16 + frr;
      af[mi2] = *(const short8*)&LD[m * 128 + ((hh * 32 + frk) ^ ((m & 7) * 8))];
    }
#pragma unroll
    for (int mi2 = 0; mi2 < 2; ++mi2)
#pragma unroll
      for (int ni = 0; ni < 4; ++ni)
        acc2[mi2][ni] = __builtin_amdgcn_mfma_f32_16x16x32_bf16(
            af[mi2], bfr[ni], acc2[mi2][ni], 0, 0, 0);

    // v-rmsnorm over 64 dims = 4 ni-frags x 16 lanes; write Ob bf16
#pragma unroll
    for (int mi2 = 0; mi2 < 2; ++mi2)
#pragma unroll
      for (int r = 0; r < 4; ++r) {
        float ss2 = 0.f;
#pragma unroll
        for (int ni = 0; ni < 4; ++ni) ss2 += acc2[mi2][ni][r] * acc2[mi2][ni][r];
        ss2 += __shfl_xor(ss2, 1, 64);
        ss2 += __shfl_xor(ss2, 2, 64);
        ss2 += __shfl_xor(ss2, 4, 64);
        ss2 += __shfl_xor(ss2, 8, 64);
        const float sc = rsqrtf(ss2 * (1.0f / HV) + 1e-5f);
        const int m = m0 + w * 32 + mi2 * 16 + rb + r;
        unsigned short* Op = Ob + (size_t)m * Hdim + (h0 + hh) * HV;
#pragma unroll
        for (int ni = 0; ni < 4; ++ni)
          Op[ni * 16 + frr] = f2bs(acc2[mi2][ni][r] * sc * wv[ni]);
      }
  }
}

extern "C" void kernel_launch(void* const* d_in, const int* in_sizes, int n_in,
                              void* d_out, int out_size, void* d_ws, size_t ws_size,
                              hipStream_t stream) {
  const float* hs = (const float*)d_in[0];
  const float* Srec = (const float*)d_in[1];
  const float* nw = (const float*)d_in[2];
  const float* qw = (const float*)d_in[3];
  const float* vnw = (const float*)d_in[4];
  const float* ow = (const float*)d_in[5];
  const float* gw = (const float*)d_in[6];

  char* ws = (char*)d_ws;
  unsigned short* X = (unsigned short*)(ws);                          // 64 MB bf16 [M,H]
  unsigned short* Ob = (unsigned short*)(ws + ((size_t)64 << 20));    // 64 MB bf16 [M,VD]
  unsigned short* qwb = (unsigned short*)(ws + ((size_t)128 << 20));  // 1 MB
  unsigned short* gwb = (unsigned short*)(ws + ((size_t)129 << 20));  // 2 MB
  unsigned short* owb = (unsigned short*)(ws + ((size_t)131 << 20));  // 2 MB
  unsigned short* Stb = (unsigned short*)(ws + ((size_t)133 << 20));  // 256 KB

  // weights f32 -> bf16 (+ S transpose)
  k_cvt<<<(KDim * Hdim / 4 + 255) / 256, 256, 0, stream>>>(
      (const float4*)qw, (uint2v*)qwb, KDim * Hdim / 4);
  k_cvt<<<(Hdim * Hdim / 4 + 255) / 256, 256, 0, stream>>>(
      (const float4*)gw, (uint2v*)gwb, Hdim * Hdim / 4);
  k_cvt<<<(Hdim * Hdim / 4 + 255) / 256, 256, 0, stream>>>(
      (const float4*)ow, (uint2v*)owb, Hdim * Hdim / 4);
  k_cvts<<<(4 * NH * HV * HK + 255) / 256, 256, 0, stream>>>(Srec, Stb);

  // x = rmsnorm(hidden) -> bf16
  k_rmsnorm<<<Mtok, 256, 0, stream>>>(hs, nw, (uint2v*)X);

  // fused q path -> Ob
  k_fused_q<<<dim3(KDim / 128, Mtok / 128), 256, 0, stream>>>(
      X, qwb, Stb, vnw, Ob);

  // fused gate+o -> d_out f32
  k_fused_go<<<dim3(Hdim / 128, Mtok / 128), 256, 0, stream>>>(
      X, Ob, gwb, owb, (float*)d_out);
}